// Round 3
// baseline (374.292 us; speedup 1.0000x reference)
//
#include <hip/hip_runtime.h>
#include <hip/hip_bf16.h>
#include <stdint.h>

// out[n,l] = 0.5*(F[n].P[idx[l,1]] + F[n].P[idx[l,2]]), F 8192x128, out 8192x10000 f32.
// Strategy: Q[l] = 0.5*(P[i1]+P[i2]) as bf16, then out = F @ Q^T via bf16 MFMA.
// Write-bound kernel (1.31 GB out): no-LDS, no-barrier GEMM; fragments direct from L2;
// operand order chosen so each lane stores float4 (4 consecutive leaves); nt stores
// bypass L2 so inputs stay cache-resident.
#define M_DIM      8192
#define K_DIM      128
#define NUM_LEAVES 10000
#define N_PAD      10112   // 79 * 128, zero-padded Q rows
#define NT         79      // leaf tiles of 128
#define MT         64      // feature-row tiles of 128

typedef __attribute__((ext_vector_type(8))) short bf16x8;
typedef __attribute__((ext_vector_type(4))) float f32x4;

static __device__ __forceinline__ unsigned short f2bf(float f) {
    union { float f; uint32_t u; } v; v.f = f;
    uint32_t u = v.u;
    u += 0x7FFFu + ((u >> 16) & 1u);   // round-to-nearest-even
    return (unsigned short)(u >> 16);
}

// fp32 features -> bf16, one float4 per thread.
__global__ void prep_features(const float* __restrict__ F, unsigned short* __restrict__ Fb) {
    int t = blockIdx.x * blockDim.x + threadIdx.x;
    float4 v = ((const float4*)F)[t];
    ushort4 o;
    o.x = f2bf(v.x); o.y = f2bf(v.y); o.z = f2bf(v.z); o.w = f2bf(v.w);
    ((ushort4*)Fb)[t] = o;
}

// Q[l][k] = 0.5*(P[idx[l,1]][k] + P[idx[l,2]][k]) bf16; rows >= NUM_LEAVES zeroed.
__global__ void prep_q(const float* __restrict__ P, const int* __restrict__ idx,
                       unsigned short* __restrict__ Qb) {
    int t = blockIdx.x * blockDim.x + threadIdx.x;
    int l = t >> 5;
    int c = (t & 31) << 2;
    ushort4 o;
    if (l < NUM_LEAVES) {
        int i1 = idx[l * 3 + 1];
        int i2 = idx[l * 3 + 2];
        float4 a = *(const float4*)&P[(size_t)i1 * K_DIM + c];
        float4 b = *(const float4*)&P[(size_t)i2 * K_DIM + c];
        o.x = f2bf(0.5f * (a.x + b.x));
        o.y = f2bf(0.5f * (a.y + b.y));
        o.z = f2bf(0.5f * (a.z + b.z));
        o.w = f2bf(0.5f * (a.w + b.w));
    } else {
        o.x = 0; o.y = 0; o.z = 0; o.w = 0;
    }
    *(ushort4*)&Qb[(size_t)l * K_DIM + c] = o;
}

// No-LDS GEMM: each wave computes a 64(leaf) x 64(row) tile.
// A-operand = Q rows (M = leaf), B-operand = F rows (N = feature row), so
// D layout (col = lane&15 = n, row = quad*4+reg = leaf) gives float4 stores.
__global__ __launch_bounds__(256, 3) void gemm_direct(
    const unsigned short* __restrict__ Fb,
    const unsigned short* __restrict__ Qb,
    float* __restrict__ out) {
    const int bn   = blockIdx.x;          // 0..78 leaf tile
    const int bm   = blockIdx.y;          // 0..63 row tile
    const int tid  = threadIdx.x;
    const int lane = tid & 63;
    const int w    = tid >> 6;
    const int wl   = (w & 1) * 64;        // leaf offset in tile
    const int wn   = (w >> 1) * 64;       // row offset in tile
    const int l15  = lane & 15;
    const int quad = lane >> 4;

    // Fragment base pointers: row = base + i*16 + l15, k chunk = quad*8 elems.
    const unsigned short* Ab = Qb + ((size_t)(bn * 128 + wl + l15)) * K_DIM + quad * 8;
    const unsigned short* Bb = Fb + ((size_t)(bm * 128 + wn + l15)) * K_DIM + quad * 8;

    f32x4 acc[4][4] = {};   // [leaf subtile][row subtile]

#pragma unroll
    for (int kt = 0; kt < 4; ++kt) {
        bf16x8 a[4], b[4];
#pragma unroll
        for (int i = 0; i < 4; ++i) {
            a[i] = *(const bf16x8*)&Ab[(size_t)i * 16 * K_DIM + kt * 32];
            b[i] = *(const bf16x8*)&Bb[(size_t)i * 16 * K_DIM + kt * 32];
        }
#pragma unroll
        for (int mi = 0; mi < 4; ++mi)
#pragma unroll
            for (int ni = 0; ni < 4; ++ni)
                acc[mi][ni] = __builtin_amdgcn_mfma_f32_16x16x32_bf16(
                    a[mi], b[ni], acc[mi][ni], 0, 0, 0);
    }

    // Store: lane holds leaves l..l+3 (reg dim) at row n; float4 nontemporal.
#pragma unroll
    for (int mi = 0; mi < 4; ++mi) {
        int l = bn * 128 + wl + mi * 16 + quad * 4;
        if (l < NUM_LEAVES) {
#pragma unroll
            for (int ni = 0; ni < 4; ++ni) {
                int n = bm * 128 + wn + ni * 16 + l15;
                __builtin_nontemporal_store(acc[mi][ni],
                    (f32x4*)&out[(size_t)n * NUM_LEAVES + l]);
            }
        }
    }
}

extern "C" void kernel_launch(void* const* d_in, const int* in_sizes, int n_in,
                              void* d_out, int out_size, void* d_ws, size_t ws_size,
                              hipStream_t stream) {
    const float* F  = (const float*)d_in[0];   // 8192*128 f32
    const float* P  = (const float*)d_in[1];   // 10101*128 f32
    const int* idx  = (const int*)d_in[2];     // 10000*3 i32
    float* out      = (float*)d_out;           // 8192*10000 f32

    unsigned short* Fb = (unsigned short*)d_ws;            // 8192*128 bf16
    unsigned short* Qb = Fb + (size_t)M_DIM * K_DIM;       // 10112*128 bf16

    prep_features<<<(M_DIM * K_DIM / 4) / 256, 256, 0, stream>>>(F, Fb);
    prep_q<<<(N_PAD * 32) / 256, 256, 0, stream>>>(P, idx, Qb);
    gemm_direct<<<dim3(NT, MT), 256, 0, stream>>>(Fb, Qb, out);
}